// Round 8
// baseline (133.839 us; speedup 1.0000x reference)
//
#include <hip/hip_runtime.h>
#include <float.h>
#include <stdint.h>

// Chamfer distance via MFMA (bf16 hi/lo compensated split), round 8.
// d[n][m] = ||t_m||^2 - 2 q_n . t_m  + ||q_n||^2 (folded into partial)
// One mfma_f32_32x32x16_bf16 computes a 32q x 32t tile of (tt - 2q.t):
//   A k-slots (query row, c = -2q): [chx chy chz clx cly clz chx chy |
//                                    chz 1 1 clx cly clz 0 0]
//   B k-slots (target col):         [bhx bhy bhz bhx bhy bhz blx bly |
//                                    blz tth ttl blx bly blz 0 0]
// B fragments prepacked by prep_kernel into ws (8 MB): H0 region = lanes
// 0-31 (k=0..7), H1 region = lanes 32-63 (k=8..15).
// R8 vs R7 (47us, 50%-occupancy-capped): LDS epilogue matrix removed
// (33.5KB -> 0), targets split across TH blocks -> 8 blocks/CU resident;
// per-query partials (min + q^2) to ws2; small reduce kernel sums.
// Loop body / A-packing / swizzle are R7-verbatim (proven, VGPR 56).

typedef short bf16x8 __attribute__((ext_vector_type(8)));
typedef float f32x16 __attribute__((ext_vector_type(16)));

#define BLK 256
#define ONE_BF 0x3F80u

__device__ __forceinline__ uint32_t bf16_rne(float f) {
    uint32_t u = __builtin_bit_cast(uint32_t, f);
    return (u + 0x7FFFu + ((u >> 16) & 1u)) >> 16;
}
__device__ __forceinline__ float bf16f(uint32_t h) {
    return __builtin_bit_cast(float, h << 16);
}

// ---- prep: 262144 points (arr0 = x, arr1 = recon), 16B H0 + 16B H1 each.
// Also zeroes the output accumulator (stream-ordered before reduce).
__global__ __launch_bounds__(BLK)
void prep_kernel(const float* __restrict__ x, const float* __restrict__ recon,
                 uint32_t* __restrict__ ws, float* __restrict__ out)
{
    int tid = blockIdx.x * BLK + threadIdx.x;     // 0..262143
    if (tid == 0) out[0] = 0.0f;
    int arr = tid >> 17;
    int p   = tid & 131071;
    const float* s = arr ? recon : x;
    float a = s[3 * p], b = s[3 * p + 1], c = s[3 * p + 2];
    uint32_t hx = bf16_rne(a), hy = bf16_rne(b), hz = bf16_rne(c);
    uint32_t lx = bf16_rne(a - bf16f(hx));
    uint32_t ly = bf16_rne(b - bf16f(hy));
    uint32_t lz = bf16_rne(c - bf16f(hz));
    float tt = a * a + b * b + c * c;
    uint32_t th = bf16_rne(tt);
    uint32_t tl = bf16_rne(tt - bf16f(th));
    uint4 H0 = make_uint4(hx | (hy << 16), hz | (hx << 16),
                          hy | (hz << 16), lx | (ly << 16));
    uint4 H1 = make_uint4(lz | (th << 16), tl | (lx << 16),
                          ly | (lz << 16), 0u);
    ((uint4*)ws)[tid]          = H0;
    ((uint4*)ws)[262144 + tid] = H1;
}

// ---- main (partial): grid 1024*TH blocks, 4 waves each, zero LDS.
// Wave owns 64 queries (2 x 32-row A-blocks) x (4096/TH) targets.
template <int TH>
__global__ __launch_bounds__(BLK)
void chamfer_mfma_p(const float* __restrict__ x, const float* __restrict__ recon,
                    const uint32_t* __restrict__ ws, float* __restrict__ ws2)
{
    // XCD-aware bijective swizzle (1024*TH % 8 == 0).
    int idx = blockIdx.x;
    constexpr int CPX = 1024 * TH / 8;
    int swz = (idx & 7) * CPX + (idx >> 3);
    int th, qb, b, dir;
    if (TH == 2) { th = swz & 1;  qb = (swz >> 1) & 15; b = (swz >> 5) & 31; dir = swz >> 10; }
    else         { th = 0;        qb = swz & 15;        b = (swz >> 4) & 31; dir = swz >> 9;  }

    const float* qsrc = dir ? recon : x;          // queries
    const int arrT = dir ? 0 : 1;                 // targets = other array

    const int tid  = threadIdx.x;
    const int wave = tid >> 6;
    const int lane = tid & 63;
    const int l31  = lane & 31;
    const int lh   = lane >> 5;

    // A fragments (R7-verbatim): row = l31 within each 32-row block.
    bf16x8 A0, A1;
    {
        int n0 = qb * 256 + wave * 64 + l31;
        #pragma unroll
        for (int rb = 0; rb < 2; ++rb) {
            const float* qp = qsrc + ((size_t)b * 4096 + n0 + rb * 32) * 3;
            float cx = -2.f * qp[0], cy = -2.f * qp[1], cz = -2.f * qp[2];
            uint32_t hx = bf16_rne(cx), hy = bf16_rne(cy), hz = bf16_rne(cz);
            uint32_t lx = bf16_rne(cx - bf16f(hx));
            uint32_t ly = bf16_rne(cy - bf16f(hy));
            uint32_t lz = bf16_rne(cz - bf16f(hz));
            uint32_t w0, w1, w2, w3;
            if (lh == 0) {
                w0 = hx | (hy << 16); w1 = hz | (lx << 16);
                w2 = ly | (lz << 16); w3 = hx | (hy << 16);
            } else {
                w0 = hz | (ONE_BF << 16); w1 = ONE_BF | (lx << 16);
                w2 = ly | (lz << 16);     w3 = 0u;
            }
            union { uint4 u; bf16x8 v; } cvt;
            cvt.u = make_uint4(w0, w1, w2, w3);
            if (rb == 0) A0 = cvt.v; else A1 = cvt.v;
        }
    }

    f32x16 zc = {0,0,0,0,0,0,0,0,0,0,0,0,0,0,0,0};
    float rmn0[16], rmn1[16];
    #pragma unroll
    for (int j = 0; j < 16; ++j) { rmn0[j] = FLT_MAX; rmn1[j] = FLT_MAX; }

    // B-fragment stream for this target half.
    const uint4* rp = (const uint4*)ws
        + (size_t)lh * 262144 + (size_t)arrT * 131072 + (size_t)b * 4096
        + (size_t)th * (2048 / TH) * TH + l31;    // th * 2048 when TH==2

    // (4096/TH)/64 iterations x 2 target-tiles, R7-verbatim body.
    constexpr int ITERS = 64 / TH;
    for (int it = 0; it < ITERS; ++it) {
        union BU { uint4 u; bf16x8 v; } B0, B1;
        B0.u = rp[0];
        B1.u = rp[32];
        rp += 64;
        f32x16 d0 = __builtin_amdgcn_mfma_f32_32x32x16_bf16(A0, B0.v, zc, 0, 0, 0);
        f32x16 d1 = __builtin_amdgcn_mfma_f32_32x32x16_bf16(A0, B1.v, zc, 0, 0, 0);
        #pragma unroll
        for (int j = 0; j < 16; ++j)
            rmn0[j] = fminf(rmn0[j], fminf(d0[j], d1[j]));
        f32x16 e0 = __builtin_amdgcn_mfma_f32_32x32x16_bf16(A1, B0.v, zc, 0, 0, 0);
        f32x16 e1 = __builtin_amdgcn_mfma_f32_32x32x16_bf16(A1, B1.v, zc, 0, 0, 0);
        #pragma unroll
        for (int j = 0; j < 16; ++j)
            rmn1[j] = fminf(rmn1[j], fminf(e0[j], e1[j]));
    }

    // Epilogue: exact cross-lane min within each 32-lane half (cols in lanes).
    #pragma unroll
    for (int j = 0; j < 16; ++j) {
        float a = rmn0[j], c = rmn1[j];
        #pragma unroll
        for (int mk = 16; mk >= 1; mk >>= 1) {
            a = fminf(a, __shfl_xor(a, mk, 64));
            c = fminf(c, __shfl_xor(c, mk, 64));
        }
        rmn0[j] = a; rmn1[j] = c;
    }

    // Writer-lane store: lane with l31 == row(j,lh) owns that query row.
    // (static j indexing only -- runtime-indexed reg arrays go to scratch)
    int n0 = qb * 256 + wave * 64 + l31;
    const float* qp0 = qsrc + ((size_t)b * 4096 + n0) * 3;
    float q2_0 = qp0[0]*qp0[0] + qp0[1]*qp0[1] + qp0[2]*qp0[2];
    float q2_1 = qp0[96]*qp0[96] + qp0[97]*qp0[97] + qp0[98]*qp0[98];
    size_t base = (((size_t)th * 2 + dir) * 32 + b) * 4096
                + (size_t)qb * 256 + (size_t)wave * 64;
    #pragma unroll
    for (int j = 0; j < 16; ++j) {
        int r = (j & 3) + 8 * (j >> 2) + 4 * lh;
        if (l31 == r) {
            ws2[base + r]      = rmn0[j] + q2_0;
            ws2[base + 32 + r] = rmn1[j] + q2_1;
        }
    }
}

// ---- reduce: min across TH halves, global mean-sum, one atomic per block.
__global__ __launch_bounds__(BLK)
void chamfer_reduce(const float* __restrict__ ws2, float* __restrict__ out,
                    int two_halves, float scale)
{
    int q = blockIdx.x * BLK + threadIdx.x;       // 0..262143
    float v = ws2[q];
    if (two_halves) v = fminf(v, ws2[262144 + q]);

    #pragma unroll
    for (int off = 32; off > 0; off >>= 1)
        v += __shfl_down(v, off, 64);

    __shared__ float red[4];
    int tid = threadIdx.x;
    if ((tid & 63) == 0) red[tid >> 6] = v;
    __syncthreads();
    if (tid == 0) {
        float s = red[0] + red[1] + red[2] + red[3];
        atomicAdd(out, s * scale);
    }
}

// ---- fallback (R7-verbatim, self-reducing): used only if ws too small.
__global__ __launch_bounds__(BLK, 3)
void chamfer_mfma_full(const float* __restrict__ x, const float* __restrict__ recon,
                       const uint32_t* __restrict__ ws, float* __restrict__ out,
                       float scale)
{
    int idx = blockIdx.x;
    int swz = (idx & 7) * 128 + (idx >> 3);
    int dir = swz >> 9;
    int b   = (swz >> 4) & 31;
    int qb  = swz & 15;
    const float* qsrc = dir ? recon : x;
    const int arrT = dir ? 0 : 1;
    const int tid  = threadIdx.x;
    const int wave = tid >> 6;
    const int lane = tid & 63;
    const int l31  = lane & 31;
    const int lh   = lane >> 5;
    bf16x8 A0, A1;
    {
        int n0 = qb * 256 + wave * 64 + l31;
        #pragma unroll
        for (int rb = 0; rb < 2; ++rb) {
            const float* qp = qsrc + ((size_t)b * 4096 + n0 + rb * 32) * 3;
            float cx = -2.f * qp[0], cy = -2.f * qp[1], cz = -2.f * qp[2];
            uint32_t hx = bf16_rne(cx), hy = bf16_rne(cy), hz = bf16_rne(cz);
            uint32_t lx = bf16_rne(cx - bf16f(hx));
            uint32_t ly = bf16_rne(cy - bf16f(hy));
            uint32_t lz = bf16_rne(cz - bf16f(hz));
            uint32_t w0, w1, w2, w3;
            if (lh == 0) { w0 = hx | (hy << 16); w1 = hz | (lx << 16);
                           w2 = ly | (lz << 16); w3 = hx | (hy << 16); }
            else         { w0 = hz | (ONE_BF << 16); w1 = ONE_BF | (lx << 16);
                           w2 = ly | (lz << 16);     w3 = 0u; }
            union { uint4 u; bf16x8 v; } cvt;
            cvt.u = make_uint4(w0, w1, w2, w3);
            if (rb == 0) A0 = cvt.v; else A1 = cvt.v;
        }
    }
    f32x16 zc = {0,0,0,0,0,0,0,0,0,0,0,0,0,0,0,0};
    float rmn0[16], rmn1[16];
    #pragma unroll
    for (int j = 0; j < 16; ++j) { rmn0[j] = FLT_MAX; rmn1[j] = FLT_MAX; }
    const uint4* rp = (const uint4*)ws
        + (size_t)lh * 262144 + (size_t)arrT * 131072 + (size_t)b * 4096 + l31;
    for (int it = 0; it < 64; ++it) {
        union BU { uint4 u; bf16x8 v; } B0, B1;
        B0.u = rp[0]; B1.u = rp[32]; rp += 64;
        f32x16 d0 = __builtin_amdgcn_mfma_f32_32x32x16_bf16(A0, B0.v, zc, 0, 0, 0);
        f32x16 d1 = __builtin_amdgcn_mfma_f32_32x32x16_bf16(A0, B1.v, zc, 0, 0, 0);
        #pragma unroll
        for (int j = 0; j < 16; ++j)
            rmn0[j] = fminf(rmn0[j], fminf(d0[j], d1[j]));
        f32x16 e0 = __builtin_amdgcn_mfma_f32_32x32x16_bf16(A1, B0.v, zc, 0, 0, 0);
        f32x16 e1 = __builtin_amdgcn_mfma_f32_32x32x16_bf16(A1, B1.v, zc, 0, 0, 0);
        #pragma unroll
        for (int j = 0; j < 16; ++j)
            rmn1[j] = fminf(rmn1[j], fminf(e0[j], e1[j]));
    }
    __shared__ float lmin[256][33];
    #pragma unroll
    for (int j = 0; j < 16; ++j) {
        int rl = (j & 3) + 8 * (j >> 2) + 4 * lh;
        lmin[wave * 64 + rl][l31]      = rmn0[j];
        lmin[wave * 64 + 32 + rl][l31] = rmn1[j];
    }
    __syncthreads();
    float m = lmin[tid][0];
    #pragma unroll
    for (int c = 1; c < 32; ++c) m = fminf(m, lmin[tid][c]);
    const float* qp = qsrc + ((size_t)b * 4096 + qb * 256 + tid) * 3;
    float v = m + qp[0] * qp[0] + qp[1] * qp[1] + qp[2] * qp[2];
    #pragma unroll
    for (int off = 32; off > 0; off >>= 1)
        v += __shfl_down(v, off, 64);
    __shared__ float red[4];
    if (lane == 0) red[wave] = v;
    __syncthreads();
    if (tid == 0)
        atomicAdd(out, (red[0] + red[1] + red[2] + red[3]) * scale);
}

extern "C" void kernel_launch(void* const* d_in, const int* in_sizes, int n_in,
                              void* d_out, int out_size, void* d_ws, size_t ws_size,
                              hipStream_t stream) {
    const float* x     = (const float*)d_in[0];
    const float* recon = (const float*)d_in[1];
    float* out = (float*)d_out;
    uint32_t* ws = (uint32_t*)d_ws;
    float* ws2 = (float*)((char*)d_ws + (size_t)8 * 1024 * 1024);

    const float scale = 1.0f / (32.0f * 4096.0f);

    prep_kernel<<<1024, BLK, 0, stream>>>(x, recon, ws, out);

    if (ws_size >= (size_t)10 * 1024 * 1024 + 512 * 1024) {
        chamfer_mfma_p<2><<<2048, BLK, 0, stream>>>(x, recon, ws, ws2);
        chamfer_reduce<<<1024, BLK, 0, stream>>>(ws2, out, 1, scale);
    } else if (ws_size >= (size_t)9 * 1024 * 1024 + 256 * 1024) {
        chamfer_mfma_p<1><<<1024, BLK, 0, stream>>>(x, recon, ws, ws2);
        chamfer_reduce<<<1024, BLK, 0, stream>>>(ws2, out, 0, scale);
    } else {
        chamfer_mfma_full<<<1024, BLK, 0, stream>>>(x, recon, ws, out, scale);
    }
}

// Round 9
// 126.396 us; speedup vs baseline: 1.0589x; 1.0589x over previous
//
#include <hip/hip_runtime.h>
#include <float.h>
#include <stdint.h>

// Chamfer distance via MFMA (bf16 hi/lo compensated split), round 9.
// d[n][m] = ||t_m||^2 - 2 q_n . t_m  + ||q_n||^2 (folded into partial)
// One mfma_f32_32x32x16_bf16 computes a 32q x 32t tile of (tt - 2q.t):
//   A k-slots (query row, c = -2q): [chx chy chz clx cly clz chx chy |
//                                    chz 1 1 clx cly clz 0 0]
//   B k-slots (target col):         [bhx bhy bhz bhx bhy bhz blx bly |
//                                    blz tth ttl blx bly blz 0 0]
// B fragments prepacked by prep_kernel into ws (8 MB): H0 region = lanes
// 0-31 (k=0..7), H1 region = lanes 32-63 (k=8..15).
// R9 = R7's proven loop + LDS epilogue, at R8's TH=2 occupancy:
//  - single shfl_xor(16) pre-fold -> lmin[256][17] (17.4 KB, 8 blocks/CU;
//    R7's [256][33]=33.5KB capped at 4; R8's all-shuffle epilogue was 3x
//    VALU cost -- 320 dependent bpermute chains. 32 shuffles is cheap.)
//  - TH=2 target split, per-query partials to ws2, tiny reduce kernel.

typedef short bf16x8 __attribute__((ext_vector_type(8)));
typedef float f32x16 __attribute__((ext_vector_type(16)));

#define BLK 256
#define ONE_BF 0x3F80u

__device__ __forceinline__ uint32_t bf16_rne(float f) {
    uint32_t u = __builtin_bit_cast(uint32_t, f);
    return (u + 0x7FFFu + ((u >> 16) & 1u)) >> 16;
}
__device__ __forceinline__ float bf16f(uint32_t h) {
    return __builtin_bit_cast(float, h << 16);
}

// ---- prep: 262144 points (arr0 = x, arr1 = recon), 16B H0 + 16B H1 each.
// Also zeroes the output accumulator (stream-ordered before reduce).
__global__ __launch_bounds__(BLK)
void prep_kernel(const float* __restrict__ x, const float* __restrict__ recon,
                 uint32_t* __restrict__ ws, float* __restrict__ out)
{
    int tid = blockIdx.x * BLK + threadIdx.x;     // 0..262143
    if (tid == 0) out[0] = 0.0f;
    int arr = tid >> 17;
    int p   = tid & 131071;
    const float* s = arr ? recon : x;
    float a = s[3 * p], b = s[3 * p + 1], c = s[3 * p + 2];
    uint32_t hx = bf16_rne(a), hy = bf16_rne(b), hz = bf16_rne(c);
    uint32_t lx = bf16_rne(a - bf16f(hx));
    uint32_t ly = bf16_rne(b - bf16f(hy));
    uint32_t lz = bf16_rne(c - bf16f(hz));
    float tt = a * a + b * b + c * c;
    uint32_t th = bf16_rne(tt);
    uint32_t tl = bf16_rne(tt - bf16f(th));
    uint4 H0 = make_uint4(hx | (hy << 16), hz | (hx << 16),
                          hy | (hz << 16), lx | (ly << 16));
    uint4 H1 = make_uint4(lz | (th << 16), tl | (lx << 16),
                          ly | (lz << 16), 0u);
    ((uint4*)ws)[tid]          = H0;
    ((uint4*)ws)[262144 + tid] = H1;
}

// ---- main (partial): 2048 blocks (XCD-swizzled), 4 waves, 17.4 KB LDS.
// Wave owns 64 queries (2 x 32-row A-blocks) x 2048 targets (half th).
__global__ __launch_bounds__(BLK)
void chamfer_mfma_p(const float* __restrict__ x, const float* __restrict__ recon,
                    const uint32_t* __restrict__ ws, float* __restrict__ ws2)
{
    // XCD-aware bijective swizzle (2048 % 8 == 0): CPX = 2048/8 = 256.
    int idx = blockIdx.x;
    int swz = (idx & 7) * 256 + (idx >> 3);
    int th  = swz & 1;
    int qb  = (swz >> 1) & 15;
    int b   = (swz >> 5) & 31;
    int dir = swz >> 10;

    const float* qsrc = dir ? recon : x;          // queries
    const int arrT = dir ? 0 : 1;                 // targets = other array

    const int tid  = threadIdx.x;
    const int wave = tid >> 6;
    const int lane = tid & 63;
    const int l31  = lane & 31;
    const int lh   = lane >> 5;

    // A fragments (R7-verbatim): row = l31 within each 32-row block.
    bf16x8 A0, A1;
    {
        int n0 = qb * 256 + wave * 64 + l31;
        #pragma unroll
        for (int rb = 0; rb < 2; ++rb) {
            const float* qp = qsrc + ((size_t)b * 4096 + n0 + rb * 32) * 3;
            float cx = -2.f * qp[0], cy = -2.f * qp[1], cz = -2.f * qp[2];
            uint32_t hx = bf16_rne(cx), hy = bf16_rne(cy), hz = bf16_rne(cz);
            uint32_t lx = bf16_rne(cx - bf16f(hx));
            uint32_t ly = bf16_rne(cy - bf16f(hy));
            uint32_t lz = bf16_rne(cz - bf16f(hz));
            uint32_t w0, w1, w2, w3;
            if (lh == 0) {
                w0 = hx | (hy << 16); w1 = hz | (lx << 16);
                w2 = ly | (lz << 16); w3 = hx | (hy << 16);
            } else {
                w0 = hz | (ONE_BF << 16); w1 = ONE_BF | (lx << 16);
                w2 = ly | (lz << 16);     w3 = 0u;
            }
            union { uint4 u; bf16x8 v; } cvt;
            cvt.u = make_uint4(w0, w1, w2, w3);
            if (rb == 0) A0 = cvt.v; else A1 = cvt.v;
        }
    }

    f32x16 zc = {0,0,0,0,0,0,0,0,0,0,0,0,0,0,0,0};
    float rmn0[16], rmn1[16];
    #pragma unroll
    for (int j = 0; j < 16; ++j) { rmn0[j] = FLT_MAX; rmn1[j] = FLT_MAX; }

    // B-fragment stream for this target half.
    const uint4* rp = (const uint4*)ws
        + (size_t)lh * 262144 + (size_t)arrT * 131072 + (size_t)b * 4096
        + (size_t)th * 2048 + l31;

    // 32 iterations x 2 target-tiles, R7-verbatim body (2 live f32x16 max).
    for (int it = 0; it < 32; ++it) {
        union BU { uint4 u; bf16x8 v; } B0, B1;
        B0.u = rp[0];
        B1.u = rp[32];
        rp += 64;
        f32x16 d0 = __builtin_amdgcn_mfma_f32_32x32x16_bf16(A0, B0.v, zc, 0, 0, 0);
        f32x16 d1 = __builtin_amdgcn_mfma_f32_32x32x16_bf16(A0, B1.v, zc, 0, 0, 0);
        #pragma unroll
        for (int j = 0; j < 16; ++j)
            rmn0[j] = fminf(rmn0[j], fminf(d0[j], d1[j]));
        f32x16 e0 = __builtin_amdgcn_mfma_f32_32x32x16_bf16(A1, B0.v, zc, 0, 0, 0);
        f32x16 e1 = __builtin_amdgcn_mfma_f32_32x32x16_bf16(A1, B1.v, zc, 0, 0, 0);
        #pragma unroll
        for (int j = 0; j < 16; ++j)
            rmn1[j] = fminf(rmn1[j], fminf(e0[j], e1[j]));
    }

    // Epilogue: one xor-16 col pre-fold (32 shuffles total), then the
    // R7-style LDS transpose at half width: lmin[256][17] = 17.4 KB.
    __shared__ float lmin[256][17];
    #pragma unroll
    for (int j = 0; j < 16; ++j) {
        int rl = (j & 3) + 8 * (j >> 2) + 4 * lh;  // verified 32x32 C/D row
        float a = fminf(rmn0[j], __shfl_xor(rmn0[j], 16, 64));
        float c = fminf(rmn1[j], __shfl_xor(rmn1[j], 16, 64));
        // lanes l31 and l31^16 hold identical values; both write same addr.
        lmin[wave * 64 + rl][l31 & 15]      = a;
        lmin[wave * 64 + 32 + rl][l31 & 15] = c;
    }
    __syncthreads();

    float m = lmin[tid][0];
    #pragma unroll
    for (int c = 1; c < 16; ++c) m = fminf(m, lmin[tid][c]);

    // Per-query partial: min + ||q||^2, coalesced store.
    const float* qp = qsrc + ((size_t)b * 4096 + qb * 256 + tid) * 3;
    float v = m + qp[0] * qp[0] + qp[1] * qp[1] + qp[2] * qp[2];
    size_t base = (((size_t)th * 2 + dir) * 32 + b) * 4096
                + (size_t)qb * 256 + tid;
    ws2[base] = v;
}

// ---- reduce: min across 2 halves, global mean-sum, one atomic per block.
__global__ __launch_bounds__(BLK)
void chamfer_reduce(const float* __restrict__ ws2, float* __restrict__ out,
                    float scale)
{
    int q = blockIdx.x * BLK + threadIdx.x;       // 0..262143
    float v = fminf(ws2[q], ws2[262144 + q]);

    #pragma unroll
    for (int off = 32; off > 0; off >>= 1)
        v += __shfl_down(v, off, 64);

    __shared__ float red[4];
    int tid = threadIdx.x;
    if ((tid & 63) == 0) red[tid >> 6] = v;
    __syncthreads();
    if (tid == 0) {
        float s = red[0] + red[1] + red[2] + red[3];
        atomicAdd(out, s * scale);
    }
}

// ---- fallback (R7-verbatim, self-reducing): used only if ws too small.
__global__ __launch_bounds__(BLK, 3)
void chamfer_mfma_full(const float* __restrict__ x, const float* __restrict__ recon,
                       const uint32_t* __restrict__ ws, float* __restrict__ out,
                       float scale)
{
    int idx = blockIdx.x;
    int swz = (idx & 7) * 128 + (idx >> 3);
    int dir = swz >> 9;
    int b   = (swz >> 4) & 31;
    int qb  = swz & 15;
    const float* qsrc = dir ? recon : x;
    const int arrT = dir ? 0 : 1;
    const int tid  = threadIdx.x;
    const int wave = tid >> 6;
    const int lane = tid & 63;
    const int l31  = lane & 31;
    const int lh   = lane >> 5;
    bf16x8 A0, A1;
    {
        int n0 = qb * 256 + wave * 64 + l31;
        #pragma unroll
        for (int rb = 0; rb < 2; ++rb) {
            const float* qp = qsrc + ((size_t)b * 4096 + n0 + rb * 32) * 3;
            float cx = -2.f * qp[0], cy = -2.f * qp[1], cz = -2.f * qp[2];
            uint32_t hx = bf16_rne(cx), hy = bf16_rne(cy), hz = bf16_rne(cz);
            uint32_t lx = bf16_rne(cx - bf16f(hx));
            uint32_t ly = bf16_rne(cy - bf16f(hy));
            uint32_t lz = bf16_rne(cz - bf16f(hz));
            uint32_t w0, w1, w2, w3;
            if (lh == 0) { w0 = hx | (hy << 16); w1 = hz | (lx << 16);
                           w2 = ly | (lz << 16); w3 = hx | (hy << 16); }
            else         { w0 = hz | (ONE_BF << 16); w1 = ONE_BF | (lx << 16);
                           w2 = ly | (lz << 16);     w3 = 0u; }
            union { uint4 u; bf16x8 v; } cvt;
            cvt.u = make_uint4(w0, w1, w2, w3);
            if (rb == 0) A0 = cvt.v; else A1 = cvt.v;
        }
    }
    f32x16 zc = {0,0,0,0,0,0,0,0,0,0,0,0,0,0,0,0};
    float rmn0[16], rmn1[16];
    #pragma unroll
    for (int j = 0; j < 16; ++j) { rmn0[j] = FLT_MAX; rmn1[j] = FLT_MAX; }
    const uint4* rp = (const uint4*)ws
        + (size_t)lh * 262144 + (size_t)arrT * 131072 + (size_t)b * 4096 + l31;
    for (int it = 0; it < 64; ++it) {
        union BU { uint4 u; bf16x8 v; } B0, B1;
        B0.u = rp[0]; B1.u = rp[32]; rp += 64;
        f32x16 d0 = __builtin_amdgcn_mfma_f32_32x32x16_bf16(A0, B0.v, zc, 0, 0, 0);
        f32x16 d1 = __builtin_amdgcn_mfma_f32_32x32x16_bf16(A0, B1.v, zc, 0, 0, 0);
        #pragma unroll
        for (int j = 0; j < 16; ++j)
            rmn0[j] = fminf(rmn0[j], fminf(d0[j], d1[j]));
        f32x16 e0 = __builtin_amdgcn_mfma_f32_32x32x16_bf16(A1, B0.v, zc, 0, 0, 0);
        f32x16 e1 = __builtin_amdgcn_mfma_f32_32x32x16_bf16(A1, B1.v, zc, 0, 0, 0);
        #pragma unroll
        for (int j = 0; j < 16; ++j)
            rmn1[j] = fminf(rmn1[j], fminf(e0[j], e1[j]));
    }
    __shared__ float lmin[256][33];
    #pragma unroll
    for (int j = 0; j < 16; ++j) {
        int rl = (j & 3) + 8 * (j >> 2) + 4 * lh;
        lmin[wave * 64 + rl][l31]      = rmn0[j];
        lmin[wave * 64 + 32 + rl][l31] = rmn1[j];
    }
    __syncthreads();
    float m = lmin[tid][0];
    #pragma unroll
    for (int c = 1; c < 32; ++c) m = fminf(m, lmin[tid][c]);
    const float* qp = qsrc + ((size_t)b * 4096 + qb * 256 + tid) * 3;
    float v = m + qp[0] * qp[0] + qp[1] * qp[1] + qp[2] * qp[2];
    #pragma unroll
    for (int off = 32; off > 0; off >>= 1)
        v += __shfl_down(v, off, 64);
    __shared__ float red[4];
    if (lane == 0) red[wave] = v;
    __syncthreads();
    if (tid == 0)
        atomicAdd(out, (red[0] + red[1] + red[2] + red[3]) * scale);
}

extern "C" void kernel_launch(void* const* d_in, const int* in_sizes, int n_in,
                              void* d_out, int out_size, void* d_ws, size_t ws_size,
                              hipStream_t stream) {
    const float* x     = (const float*)d_in[0];
    const float* recon = (const float*)d_in[1];
    float* out = (float*)d_out;
    uint32_t* ws = (uint32_t*)d_ws;
    float* ws2 = (float*)((char*)d_ws + (size_t)8 * 1024 * 1024);

    const float scale = 1.0f / (32.0f * 4096.0f);

    prep_kernel<<<1024, BLK, 0, stream>>>(x, recon, ws, out);

    if (ws_size >= (size_t)10 * 1024 * 1024 + 512 * 1024) {
        chamfer_mfma_p<<<2048, BLK, 0, stream>>>(x, recon, ws, ws2);
        chamfer_reduce<<<1024, BLK, 0, stream>>>(ws2, out, scale);
    } else {
        chamfer_mfma_full<<<1024, BLK, 0, stream>>>(x, recon, ws, out, scale);
    }
}